// Round 6
// baseline (594.724 us; speedup 1.0000x reference)
//
#include <hip/hip_runtime.h>
#include <math.h>

#define DD 128
#define HH 256

typedef __attribute__((ext_vector_type(8))) short bf16x8;
typedef __attribute__((ext_vector_type(4))) float f32x4;
typedef __attribute__((ext_vector_type(2))) float f32x2;
typedef unsigned short u16;
typedef unsigned int u32;

__device__ __forceinline__ float bf2f(u16 u) {
  union { u32 i; float f; } v; v.i = ((u32)u) << 16; return v.f;
}
__device__ __forceinline__ u16 f2bf(float f) {
  union { u32 i; float f; } v; v.f = f;
  u32 r = v.i + 0x7FFFu + ((v.i >> 16) & 1u);
  return (u16)(r >> 16);
}
__device__ __forceinline__ u32 pack2(float a, float b) {
  return (u32)f2bf(a) | ((u32)f2bf(b) << 16);
}

// vectorized sigmoid(f32) -> bf16; ef reads nontemporal (don't evict sbf from L3)
__global__ __launch_bounds__(256) void sigmoid8_f32_bf16(const float* __restrict__ in,
                                                         uint4* __restrict__ out, int n8) {
  int i = blockIdx.x * 256 + threadIdx.x;
  int stride = gridDim.x * 256;
  for (; i < n8; i += stride) {
    const f32x4 a = __builtin_nontemporal_load(((const f32x4*)in) + i * 2);
    const f32x4 b = __builtin_nontemporal_load(((const f32x4*)in) + i * 2 + 1);
    float s0 = 1.f / (1.f + __expf(-a.x));
    float s1 = 1.f / (1.f + __expf(-a.y));
    float s2 = 1.f / (1.f + __expf(-a.z));
    float s3 = 1.f / (1.f + __expf(-a.w));
    float s4 = 1.f / (1.f + __expf(-b.x));
    float s5 = 1.f / (1.f + __expf(-b.y));
    float s6 = 1.f / (1.f + __expf(-b.z));
    float s7 = 1.f / (1.f + __expf(-b.w));
    out[i] = make_uint4(pack2(s0, s1), pack2(s2, s3), pack2(s4, s5), pack2(s6, s7));
  }
}

// all 4 weight transposes in one launch: [K][N] f32 -> [N][K] bf16
__global__ __launch_bounds__(256) void transpose_all(
    const float* __restrict__ W1a, const float* __restrict__ W1b,
    const float* __restrict__ W2a, const float* __restrict__ W2b,
    u16* __restrict__ o1, u16* __restrict__ o2,
    u16* __restrict__ o3, u16* __restrict__ o4) {
  const int total = 4 * DD * HH;
  int idx = blockIdx.x * 256 + threadIdx.x;
  int stride = gridDim.x * 256;
  for (; idx < total; idx += stride) {
    int m = idx >> 15;          // DD*HH = 32768
    int r = idx & 32767;
    const float* in; u16* out; int K, Nc;
    if (m == 0)      { in = W1a; out = o1; K = DD; Nc = HH; }
    else if (m == 1) { in = W1b; out = o2; K = HH; Nc = DD; }
    else if (m == 2) { in = W2a; out = o3; K = DD; Nc = HH; }
    else             { in = W2b; out = o4; K = HH; Nc = DD; }
    int k = r / Nc, n = r % Nc;
    out[n * K + k] = f2bf(in[r]);
  }
}

// tiny FCNN on the global feature vector (fp32, one block)
__global__ __launch_bounds__(256) void g3_kernel(const float* __restrict__ g,
    const float* __restrict__ W3a, const float* __restrict__ b3a,
    const float* __restrict__ W3b, const float* __restrict__ b3b,
    float* __restrict__ g3out) {
  __shared__ float gs[DD];
  __shared__ float hs[HH];
  int t = threadIdx.x;
  if (t < DD) gs[t] = g[t];
  __syncthreads();
  float acc = b3a[t];
  for (int k = 0; k < DD; ++k) acc = fmaf(gs[k], W3a[k * HH + t], acc);
  hs[t] = acc > 0.f ? acc : 0.f;
  __syncthreads();
  if (t < DD) {
    float o = b3b[t];
    for (int j = 0; j < HH; ++j) o = fmaf(hs[j], W3b[j * DD + t], o);
    g3out[t] = o;
  }
}

// Fused both FCNNs: per block (4 waves) one 16-row tile of x.
// x fp32 -> bf16 A-frags in regs; hid1/hid2 via MFMA into XOR-swizzled LDS
// (slot^row swizzle: K-frag ds_reads would otherwise be a 16-way bank conflict);
// second layer MFMA reads LDS; only h1/h2 bf16 hit HBM.
__global__ __launch_bounds__(256) void fcnn_fused(const float* __restrict__ x,
    const u16* __restrict__ w1aT, const float* __restrict__ b1a,
    const u16* __restrict__ w1bT, const float* __restrict__ b1b,
    const u16* __restrict__ w2aT, const float* __restrict__ b2a,
    const u16* __restrict__ w2bT, const float* __restrict__ b2b,
    u16* __restrict__ h1, u16* __restrict__ h2, int N) {
  __shared__ u16 hid[2][16 * HH];   // 16 KB, swizzled
  const int m0 = blockIdx.x * 16;
  const int w = threadIdx.x >> 6;
  const int lane = threadIdx.x & 63;
  const int l15 = lane & 15, l4 = lane >> 4;

  // A fragments: x[m0+l15][kb*32 + l4*8 + i], fp32 -> bf16
  int rowA = m0 + l15; if (rowA >= N) rowA = N - 1;
  const float* xr = x + (size_t)rowA * DD + l4 * 8;
  bf16x8 ax[4];
#pragma unroll
  for (int kb = 0; kb < 4; ++kb) {
    f32x4 a = *(const f32x4*)(xr + kb * 32);
    f32x4 b = *(const f32x4*)(xr + kb * 32 + 4);
    bf16x8 v;
    v[0] = (short)f2bf(a.x); v[1] = (short)f2bf(a.y);
    v[2] = (short)f2bf(a.z); v[3] = (short)f2bf(a.w);
    v[4] = (short)f2bf(b.x); v[5] = (short)f2bf(b.y);
    v[6] = (short)f2bf(b.z); v[7] = (short)f2bf(b.w);
    ax[kb] = v;
  }

  // Layer 1 of both FCNNs: hid[f] = relu(x @ Wfa + bfa), wave w does cols [w*64, w*64+64)
#pragma unroll
  for (int f = 0; f < 2; ++f) {
    const u16* wT = f ? w2aT : w1aT;
    const float* bs = f ? b2a : b1a;
    bf16x8 bf[4][4];
    float bias4[4];
#pragma unroll
    for (int t = 0; t < 4; ++t) {
      const int col = w * 64 + t * 16 + l15;
      const u16* bb = wT + (size_t)col * DD + l4 * 8;
#pragma unroll
      for (int kb = 0; kb < 4; ++kb) bf[kb][t] = *(const bf16x8*)(bb + kb * 32);
      bias4[t] = bs[col];
    }
    f32x4 acc[4] = {};
#pragma unroll
    for (int kb = 0; kb < 4; ++kb)
#pragma unroll
      for (int t = 0; t < 4; ++t)
        acc[t] = __builtin_amdgcn_mfma_f32_16x16x32_bf16(ax[kb], bf[kb][t], acc[t], 0, 0, 0);
#pragma unroll
    for (int t = 0; t < 4; ++t) {
      const int col = w * 64 + t * 16 + l15;
      const int slot = col >> 3, within = col & 7;
#pragma unroll
      for (int r = 0; r < 4; ++r) {
        const int row = l4 * 4 + r;
        float v = acc[t][r] + bias4[t];
        v = v > 0.f ? v : 0.f;
        hid[f][row * HH + ((slot ^ row) << 3) + within] = f2bf(v);
      }
    }
  }
  __syncthreads();

  // Layer 2: waves 0,1 -> h1 (from hid[0], W1b); waves 2,3 -> h2 (from hid[1], W2b)
  {
    const int f = w >> 1;
    const u16* wT = f ? w2bT : w1bT;
    const float* bs = f ? b2b : b1b;
    u16* Dst = f ? h2 : h1;
    const int c0 = (w & 1) * 64;

    bf16x8 ah[8];
#pragma unroll
    for (int kb = 0; kb < 8; ++kb) {
      const int slot = kb * 4 + l4;
      ah[kb] = *(const bf16x8*)&hid[f][l15 * HH + ((slot ^ l15) << 3)];
    }
    float bias4[4];
#pragma unroll
    for (int t = 0; t < 4; ++t) bias4[t] = bs[c0 + t * 16 + l15];
    f32x4 acc[4] = {};
#pragma unroll 2
    for (int kb = 0; kb < 8; ++kb) {
      bf16x8 bf3[4];
#pragma unroll
      for (int t = 0; t < 4; ++t)
        bf3[t] = *(const bf16x8*)(wT + (size_t)(c0 + t * 16 + l15) * HH + kb * 32 + l4 * 8);
#pragma unroll
      for (int t = 0; t < 4; ++t)
        acc[t] = __builtin_amdgcn_mfma_f32_16x16x32_bf16(ah[kb], bf3[t], acc[t], 0, 0, 0);
    }
#pragma unroll
    for (int t = 0; t < 4; ++t)
#pragma unroll
      for (int r = 0; r < 4; ++r) {
        const int row = m0 + l4 * 4 + r;
        if (row < N) Dst[(size_t)row * DD + c0 + t * 16 + l15] = f2bf(acc[t][r] + bias4[t]);
      }
  }
}

// ---- CSR build ----
__global__ __launch_bounds__(256) void count_kernel(const int* __restrict__ eix,
                                                    u32* __restrict__ deg, int twoE) {
  int t = blockIdx.x * 256 + threadIdx.x;
  int stride = gridDim.x * 256;
  for (; t < twoE; t += stride) atomicAdd(&deg[eix[t]], 1u);
}

// 16-wave coalesced two-pass scan (single block)
__global__ __launch_bounds__(1024) void scan_kernel(const u32* __restrict__ deg,
    u32* __restrict__ rowstart, u32* __restrict__ cursor, int N) {
  __shared__ u32 wsum[16];
  const int t = threadIdx.x;
  const int w = t >> 6, lane = t & 63;
  const int span = ((N + 1023) & ~1023) >> 4;   // multiple of 64
  const int b = w * span;
  const int e = min(b + span, N);

  u32 s = 0;
  for (int i = b + lane; i < e; i += 64) s += deg[i];
#pragma unroll
  for (int off = 32; off; off >>= 1) s += __shfl_xor(s, off);
  if (lane == 0) wsum[w] = s;
  __syncthreads();

  u32 carry = 0;
  for (int i = 0; i < w; ++i) carry += wsum[i];

  for (int i0 = b; i0 < e; i0 += 64) {
    int i = i0 + lane;
    u32 v = (i < e) ? deg[i] : 0u;
    u32 inc = v;
#pragma unroll
    for (int off = 1; off < 64; off <<= 1) {
      u32 u2 = __shfl_up(inc, off);
      if (lane >= off) inc += u2;
    }
    u32 excl = carry + inc - v;
    if (i < e) { rowstart[i] = excl; cursor[i] = excl; }
    carry += __shfl(inc, 63);
  }
  if (w == 15 && lane == 63) rowstart[N] = carry;
}

__global__ __launch_bounds__(256) void scatter_kernel(const int* __restrict__ eix,
    u32* __restrict__ cursor, uint2* __restrict__ adj, int E) {
  int t = blockIdx.x * 256 + threadIdx.x;
  int stride = gridDim.x * 256;
  int twoE = 2 * E;
  for (; t < twoE; t += stride) {
    int node, eid, other;
    if (t < E) { node = eix[t]; eid = t;     other = eix[t + E]; }
    else       { node = eix[t]; eid = t - E; other = eix[t - E]; }
    u32 pos = atomicAdd(&cursor[node], 1u);
    adj[pos] = make_uint2((u32)eid, (u32)other);
  }
}

// ---- fused gather + instance-norm + residual ----
#define ACC2(su, hu)                                        \
  {                                                         \
    float sx_ = bf2f((u16)((su) & 0xffffu));                \
    float sy_ = bf2f((u16)((su) >> 16));                    \
    dx += sx_; dy += sy_;                                   \
    ax = fmaf(sx_, bf2f((u16)((hu) & 0xffffu)), ax);        \
    ay = fmaf(sy_, bf2f((u16)((hu) >> 16)), ay);            \
  }

template<bool SB>
__global__ __launch_bounds__(256) void gather_final(const float* __restrict__ x,
    const u16* __restrict__ h1, const u16* __restrict__ h2,
    const float* __restrict__ ef, const u16* __restrict__ sbf,
    const uint2* __restrict__ adj, const u32* __restrict__ rowstart,
    const float* __restrict__ g3, float* __restrict__ out, int N) {
  int row0 = (blockIdx.x * 256 + threadIdx.x) >> 6;
  if (row0 >= N) return;
  const int row = __builtin_amdgcn_readfirstlane(row0);
  const int lane = threadIdx.x & 63;
  const int d0 = lane * 2;

  const u32 beg = rowstart[row];
  const u32 end = rowstart[row + 1];

  float dx = 0.f, dy = 0.f, ax = 0.f, ay = 0.f;
  u32 j = beg;
  if (SB) {
    for (; j + 8 <= end; j += 8) {
      uint2 e[8];
      u32 sv[8], hv[8];
#pragma unroll
      for (int q = 0; q < 8; ++q) e[q] = adj[j + q];
#pragma unroll
      for (int q = 0; q < 8; ++q) {
        sv[q] = *(const u32*)(sbf + (size_t)e[q].x * DD + d0);
        hv[q] = *(const u32*)(h2  + (size_t)e[q].y * DD + d0);
      }
#pragma unroll
      for (int q = 0; q < 8; ++q) ACC2(sv[q], hv[q])
    }
    for (; j + 2 <= end; j += 2) {
      const uint2 e0 = adj[j + 0];
      const uint2 e1 = adj[j + 1];
      u32 s0 = *(const u32*)(sbf + (size_t)e0.x * DD + d0);
      u32 h0 = *(const u32*)(h2  + (size_t)e0.y * DD + d0);
      u32 s1 = *(const u32*)(sbf + (size_t)e1.x * DD + d0);
      u32 h1v = *(const u32*)(h2 + (size_t)e1.y * DD + d0);
      ACC2(s0, h0) ACC2(s1, h1v)
    }
  }
  for (; j < end; ++j) {
    uint2 en = adj[j];
    u32 su, hu;
    if (SB) {
      su = *(const u32*)(sbf + (size_t)en.x * DD + d0);
    } else {
      f32x2 e2 = *(const f32x2*)(ef + (size_t)en.x * DD + d0);
      su = pack2(1.f / (1.f + __expf(-e2.x)), 1.f / (1.f + __expf(-e2.y)));
    }
    hu = *(const u32*)(h2 + (size_t)en.y * DD + d0);
    ACC2(su, hu)
  }

  const size_t base = (size_t)row * DD + d0;
  f32x2 xv = __builtin_nontemporal_load((const f32x2*)(x + base));
  u32 h1u = __builtin_nontemporal_load((const u32*)(h1 + base));
  f32x2 gv = *(const f32x2*)(g3 + d0);

  float i0 = bf2f((u16)(h1u & 0xffffu)) + ax / (dx + 1e-7f) + gv.x;
  float i1 = bf2f((u16)(h1u >> 16)) + ay / (dy + 1e-7f) + gv.y;

  float s = i0 + i1;
  float q = i0 * i0 + i1 * i1;
#pragma unroll
  for (int off = 32; off; off >>= 1) {
    s += __shfl_xor(s, off);
    q += __shfl_xor(q, off);
  }
  float mean = s * (1.f / 128.f);
  float var = q * (1.f / 128.f) - mean * mean;
  float rstd = rsqrtf(var + 1e-5f);
  float n0v = (i0 - mean) * rstd;
  float n1v = (i1 - mean) * rstd;
  f32x2 ov;
  ov.x = xv.x + (n0v > 0.f ? n0v : 0.f);
  ov.y = xv.y + (n1v > 0.f ? n1v : 0.f);
  __builtin_nontemporal_store(ov, (f32x2*)(out + base));
}

extern "C" void kernel_launch(void* const* d_in, const int* in_sizes, int n_in,
                              void* d_out, int out_size, void* d_ws, size_t ws_size,
                              hipStream_t stream) {
  const float* x   = (const float*)d_in[0];
  const int*   eix = (const int*)d_in[1];
  const float* ef  = (const float*)d_in[2];
  const float* gf  = (const float*)d_in[3];
  const float* W1a = (const float*)d_in[4];
  const float* b1a = (const float*)d_in[5];
  const float* W1b = (const float*)d_in[6];
  const float* b1b = (const float*)d_in[7];
  const float* W2a = (const float*)d_in[8];
  const float* b2a = (const float*)d_in[9];
  const float* W2b = (const float*)d_in[10];
  const float* b2b = (const float*)d_in[11];
  const float* W3a = (const float*)d_in[12];
  const float* b3a = (const float*)d_in[13];
  const float* W3b = (const float*)d_in[14];
  const float* b3b = (const float*)d_in[15];

  const int N = in_sizes[0] / DD;
  const int E = in_sizes[2] / DD;

  char* p = (char*)d_ws;
  auto take = [&](size_t bytes) -> char* {
    char* r = p;
    p += (bytes + 255) & ~(size_t)255;
    return r;
  };
  u16* w1aT  = (u16*)take((size_t)DD * HH * 2);
  u16* w1bT  = (u16*)take((size_t)DD * HH * 2);
  u16* w2aT  = (u16*)take((size_t)DD * HH * 2);
  u16* w2bT  = (u16*)take((size_t)DD * HH * 2);
  u16* h1b   = (u16*)take((size_t)N * DD * 2);
  u16* h2b   = (u16*)take((size_t)N * DD * 2);
  u32* deg   = (u32*)take((size_t)N * 4);
  u32* rowst = (u32*)take((size_t)(N + 1) * 4);
  u32* curs  = (u32*)take((size_t)N * 4);
  uint2* adj = (uint2*)take((size_t)2 * E * 8);
  float* g3  = (float*)take((size_t)DD * 4);
  size_t sBytes = (size_t)E * DD * 2;
  bool useS = ((size_t)(p - (char*)d_ws) + sBytes) <= ws_size;
  u16* sbf = useS ? (u16*)take(sBytes) : nullptr;

  hipMemsetAsync(deg, 0, (size_t)N * 4, stream);

  transpose_all<<<512, 256, 0, stream>>>(W1a, W1b, W2a, W2b, w1aT, w1bT, w2aT, w2bT);
  g3_kernel<<<1, 256, 0, stream>>>(gf, W3a, b3a, W3b, b3b, g3);

  // CSR build
  count_kernel<<<2048, 256, 0, stream>>>(eix, deg, 2 * E);
  scan_kernel<<<1, 1024, 0, stream>>>(deg, rowst, curs, N);
  scatter_kernel<<<2048, 256, 0, stream>>>(eix, curs, adj, E);

  // both FCNNs fused (x read fp32, hid in LDS, h1/h2 bf16 out)
  fcnn_fused<<<(N + 15) / 16, 256, 0, stream>>>(x, w1aT, b1a, w1bT, b1b,
                                                w2aT, b2a, w2bT, b2b, h1b, h2b, N);

  // sigmoid last so sbf is L3-resident for gather
  if (useS) sigmoid8_f32_bf16<<<4096, 256, 0, stream>>>(ef, (uint4*)sbf, E * DD / 8);

  if (useS)
    gather_final<true ><<<(N + 3) / 4, 256, 0, stream>>>(x, h1b, h2b, ef, sbf, adj,
                                                         rowst, g3, (float*)d_out, N);
  else
    gather_final<false><<<(N + 3) / 4, 256, 0, stream>>>(x, h1b, h2b, ef, nullptr, adj,
                                                         rowst, g3, (float*)d_out, N);
}

// Round 7
// 494.054 us; speedup vs baseline: 1.2038x; 1.2038x over previous
//
#include <hip/hip_runtime.h>
#include <math.h>

#define DD 128
#define HH 256

typedef __attribute__((ext_vector_type(8))) short bf16x8;
typedef __attribute__((ext_vector_type(4))) float f32x4;
typedef __attribute__((ext_vector_type(2))) float f32x2;
typedef unsigned short u16;
typedef unsigned int u32;

__device__ __forceinline__ float bf2f(u16 u) {
  union { u32 i; float f; } v; v.i = ((u32)u) << 16; return v.f;
}
__device__ __forceinline__ u16 f2bf(float f) {
  union { u32 i; float f; } v; v.f = f;
  u32 r = v.i + 0x7FFFu + ((v.i >> 16) & 1u);
  return (u16)(r >> 16);
}
__device__ __forceinline__ u32 pack2(float a, float b) {
  return (u32)f2bf(a) | ((u32)f2bf(b) << 16);
}

// vectorized f32 -> bf16 (8 elems/thread)
__global__ __launch_bounds__(256) void conv8_f32_bf16(const float* __restrict__ in,
                                                      uint4* __restrict__ out, int n8) {
  int i = blockIdx.x * 256 + threadIdx.x;
  int stride = gridDim.x * 256;
  for (; i < n8; i += stride) {
    const f32x4 a = ((const f32x4*)in)[i * 2];
    const f32x4 b = ((const f32x4*)in)[i * 2 + 1];
    out[i] = make_uint4(pack2(a.x, a.y), pack2(a.z, a.w),
                        pack2(b.x, b.y), pack2(b.z, b.w));
  }
}

// all 4 weight transposes in one launch: [K][N] f32 -> [N][K] bf16
__global__ __launch_bounds__(256) void transpose_all(
    const float* __restrict__ W1a, const float* __restrict__ W1b,
    const float* __restrict__ W2a, const float* __restrict__ W2b,
    u16* __restrict__ o1, u16* __restrict__ o2,
    u16* __restrict__ o3, u16* __restrict__ o4) {
  const int total = 4 * DD * HH;
  int idx = blockIdx.x * 256 + threadIdx.x;
  int stride = gridDim.x * 256;
  for (; idx < total; idx += stride) {
    int m = idx >> 15;          // DD*HH = 32768
    int r = idx & 32767;
    const float* in; u16* out; int K, Nc;
    if (m == 0)      { in = W1a; out = o1; K = DD; Nc = HH; }
    else if (m == 1) { in = W1b; out = o2; K = HH; Nc = DD; }
    else if (m == 2) { in = W2a; out = o3; K = DD; Nc = HH; }
    else             { in = W2b; out = o4; K = HH; Nc = DD; }
    int k = r / Nc, n = r % Nc;
    out[n * K + k] = f2bf(in[r]);
  }
}

// tiny FCNN on the global feature vector (fp32, one block)
__global__ __launch_bounds__(256) void g3_kernel(const float* __restrict__ g,
    const float* __restrict__ W3a, const float* __restrict__ b3a,
    const float* __restrict__ W3b, const float* __restrict__ b3b,
    float* __restrict__ g3out) {
  __shared__ float gs[DD];
  __shared__ float hs[HH];
  int t = threadIdx.x;
  if (t < DD) gs[t] = g[t];
  __syncthreads();
  float acc = b3a[t];
  for (int k = 0; k < DD; ++k) acc = fmaf(gs[k], W3a[k * HH + t], acc);
  hs[t] = acc > 0.f ? acc : 0.f;
  __syncthreads();
  if (t < DD) {
    float o = b3b[t];
    for (int j = 0; j < HH; ++j) o = fmaf(hs[j], W3b[j * DD + t], o);
    g3out[t] = o;
  }
}

// C[M,NCOLS] = A[M,K] @ B + bias (optional relu); BT = B^T [NCOLS][K] bf16.
// One wave: 16 rows x 64 cols, B-frags in regs across the whole M sweep.
template<int K, int NCOLS, bool RELU>
__global__ __launch_bounds__(256) void gemm_w64(const u16* __restrict__ A,
    const u16* __restrict__ BT, const float* __restrict__ bias,
    u16* __restrict__ Dst, int M) {
  const int wave = (blockIdx.x * 256 + threadIdx.x) >> 6;
  const int lane = threadIdx.x & 63;
  const int totalWaves = (gridDim.x * 256) >> 6;
  constexpr int nChunks = NCOLS / 64;
  const int nc = wave % nChunks;
  const int mw = wave / nChunks;
  const int mStride = totalWaves / nChunks;
  const int l15 = lane & 15;
  const int l4 = lane >> 4;
  constexpr int KB = K / 32;

  bf16x8 bfrag[KB][4];
  float bcol[4];
#pragma unroll
  for (int t = 0; t < 4; ++t) {
    const int col = nc * 64 + t * 16 + l15;
    const u16* bbase = BT + (size_t)col * K + l4 * 8;
#pragma unroll
    for (int kb = 0; kb < KB; ++kb) bfrag[kb][t] = *(const bf16x8*)(bbase + kb * 32);
    bcol[t] = bias[col];
  }

  const int mTiles = M >> 4;  // M multiple of 16
  for (int mt = mw; mt < mTiles; mt += mStride) {
    const int m0 = mt << 4;
    const u16* arow = A + (size_t)(m0 + l15) * K + l4 * 8;
    f32x4 acc[4] = {{0,0,0,0},{0,0,0,0},{0,0,0,0},{0,0,0,0}};
#pragma unroll
    for (int kb = 0; kb < KB; ++kb) {
      bf16x8 afrag = *(const bf16x8*)(arow + kb * 32);
#pragma unroll
      for (int t = 0; t < 4; ++t)
        acc[t] = __builtin_amdgcn_mfma_f32_16x16x32_bf16(afrag, bfrag[kb][t], acc[t], 0, 0, 0);
    }
#pragma unroll
    for (int t = 0; t < 4; ++t) {
#pragma unroll
      for (int r = 0; r < 4; ++r) {
        const int row = m0 + l4 * 4 + r;
        float v = acc[t][r] + bcol[t];
        if (RELU) v = v > 0.f ? v : 0.f;
        Dst[(size_t)row * NCOLS + nc * 64 + t * 16 + l15] = f2bf(v);
      }
    }
  }
}

// ---- CSR build ----
__global__ __launch_bounds__(256) void count_kernel(const int* __restrict__ eix,
                                                    u32* __restrict__ deg, int twoE) {
  int t = blockIdx.x * 256 + threadIdx.x;
  int stride = gridDim.x * 256;
  for (; t < twoE; t += stride) atomicAdd(&deg[eix[t]], 1u);
}

// 16-wave coalesced two-pass scan (single block)
__global__ __launch_bounds__(1024) void scan_kernel(const u32* __restrict__ deg,
    u32* __restrict__ rowstart, u32* __restrict__ cursor, int N) {
  __shared__ u32 wsum[16];
  const int t = threadIdx.x;
  const int w = t >> 6, lane = t & 63;
  const int span = ((N + 1023) & ~1023) >> 4;   // multiple of 64
  const int b = w * span;
  const int e = min(b + span, N);

  u32 s = 0;
  for (int i = b + lane; i < e; i += 64) s += deg[i];
#pragma unroll
  for (int off = 32; off; off >>= 1) s += __shfl_xor(s, off);
  if (lane == 0) wsum[w] = s;
  __syncthreads();

  u32 carry = 0;
  for (int i = 0; i < w; ++i) carry += wsum[i];

  for (int i0 = b; i0 < e; i0 += 64) {
    int i = i0 + lane;
    u32 v = (i < e) ? deg[i] : 0u;
    u32 inc = v;
#pragma unroll
    for (int off = 1; off < 64; off <<= 1) {
      u32 u2 = __shfl_up(inc, off);
      if (lane >= off) inc += u2;
    }
    u32 excl = carry + inc - v;
    if (i < e) { rowstart[i] = excl; cursor[i] = excl; }
    carry += __shfl(inc, 63);
  }
  if (w == 15 && lane == 63) rowstart[N] = carry;
}

// scatter: adjO[pos] = other node; posrec[e] = (src-side pos, dst-side pos)
__global__ __launch_bounds__(256) void scatter_kernel(const int* __restrict__ eix,
    u32* __restrict__ cursor, u32* __restrict__ adjO, uint2* __restrict__ posrec, int E) {
  int t = blockIdx.x * 256 + threadIdx.x;
  int stride = gridDim.x * 256;
  int twoE = 2 * E;
  for (; t < twoE; t += stride) {
    int node, eid, other;
    bool isSrc = (t < E);
    if (isSrc) { node = eix[t]; eid = t;     other = eix[t + E]; }
    else       { node = eix[t]; eid = t - E; other = eix[t - E]; }
    u32 pos = atomicAdd(&cursor[node], 1u);
    adjO[pos] = (u32)other;
    if (isSrc) posrec[eid].x = pos; else posrec[eid].y = pos;
  }
}

// fallback scatter (uint2 adj with eid) if ws can't hold sPerm
__global__ __launch_bounds__(256) void scatter_eid(const int* __restrict__ eix,
    u32* __restrict__ cursor, uint2* __restrict__ adj, int E) {
  int t = blockIdx.x * 256 + threadIdx.x;
  int stride = gridDim.x * 256;
  int twoE = 2 * E;
  for (; t < twoE; t += stride) {
    int node, eid, other;
    if (t < E) { node = eix[t]; eid = t;     other = eix[t + E]; }
    else       { node = eix[t]; eid = t - E; other = eix[t - E]; }
    u32 pos = atomicAdd(&cursor[node], 1u);
    adj[pos] = make_uint2((u32)eid, (u32)other);
  }
}

// one wave per edge: coalesced ef read, sigmoid, write s (bf16x2 per lane) into
// BOTH CSR slots of this edge. Scattered writes are fire-and-forget.
__global__ __launch_bounds__(256) void sigmoid_scatter(const float* __restrict__ ef,
    const uint2* __restrict__ posrec, u32* __restrict__ sPerm, int E) {
  const int e = (blockIdx.x * 256 + threadIdx.x) >> 6;
  if (e >= E) return;
  const int lane = threadIdx.x & 63;
  f32x2 v = __builtin_nontemporal_load((const f32x2*)(ef + (size_t)e * DD + lane * 2));
  u32 s = pack2(1.f / (1.f + __expf(-v.x)), 1.f / (1.f + __expf(-v.y)));
  uint2 pr = posrec[e];
  sPerm[(size_t)pr.x * 64 + lane] = s;
  sPerm[(size_t)pr.y * 64 + lane] = s;
}

#define ACC2(su, hu)                                        \
  {                                                         \
    float sx_ = bf2f((u16)((su) & 0xffffu));                \
    float sy_ = bf2f((u16)((su) >> 16));                    \
    dx += sx_; dy += sy_;                                   \
    ax = fmaf(sx_, bf2f((u16)((hu) & 0xffffu)), ax);        \
    ay = fmaf(sy_, bf2f((u16)((hu) >> 16)), ay);            \
  }

// gather with sequential s reads: s[j] at CSR position j, other-node id adjO[j]
__global__ __launch_bounds__(256) void gather_seq(const float* __restrict__ x,
    const u16* __restrict__ h1, const u16* __restrict__ h2,
    const u32* __restrict__ sPerm, const u32* __restrict__ adjO,
    const u32* __restrict__ rowstart, const float* __restrict__ g3,
    float* __restrict__ out, int N) {
  int row0 = (blockIdx.x * 256 + threadIdx.x) >> 6;
  if (row0 >= N) return;
  const int row = __builtin_amdgcn_readfirstlane(row0);
  const int lane = threadIdx.x & 63;
  const int d0 = lane * 2;

  const u32 beg = rowstart[row];
  const u32 end = rowstart[row + 1];

  float dx = 0.f, dy = 0.f, ax = 0.f, ay = 0.f;
  u32 j = beg;
  for (; j + 8 <= end; j += 8) {
    u32 oth[8], sv[8], hv[8];
#pragma unroll
    for (int q = 0; q < 8; ++q) oth[q] = adjO[j + q];
#pragma unroll
    for (int q = 0; q < 8; ++q) sv[q] = sPerm[(size_t)(j + q) * 64 + lane];
#pragma unroll
    for (int q = 0; q < 8; ++q) hv[q] = *(const u32*)(h2 + (size_t)oth[q] * DD + d0);
#pragma unroll
    for (int q = 0; q < 8; ++q) ACC2(sv[q], hv[q])
  }
  for (; j < end; ++j) {
    u32 o = adjO[j];
    u32 su = sPerm[(size_t)j * 64 + lane];
    u32 hu = *(const u32*)(h2 + (size_t)o * DD + d0);
    ACC2(su, hu)
  }

  const size_t base = (size_t)row * DD + d0;
  f32x2 xv = __builtin_nontemporal_load((const f32x2*)(x + base));
  u32 h1u = __builtin_nontemporal_load((const u32*)(h1 + base));
  f32x2 gv = *(const f32x2*)(g3 + d0);

  float i0 = bf2f((u16)(h1u & 0xffffu)) + ax / (dx + 1e-7f) + gv.x;
  float i1 = bf2f((u16)(h1u >> 16)) + ay / (dy + 1e-7f) + gv.y;

  float s = i0 + i1;
  float q = i0 * i0 + i1 * i1;
#pragma unroll
  for (int off = 32; off; off >>= 1) {
    s += __shfl_xor(s, off);
    q += __shfl_xor(q, off);
  }
  float mean = s * (1.f / 128.f);
  float var = q * (1.f / 128.f) - mean * mean;
  float rstd = rsqrtf(var + 1e-5f);
  float n0v = (i0 - mean) * rstd;
  float n1v = (i1 - mean) * rstd;
  f32x2 ov;
  ov.x = xv.x + (n0v > 0.f ? n0v : 0.f);
  ov.y = xv.y + (n1v > 0.f ? n1v : 0.f);
  __builtin_nontemporal_store(ov, (f32x2*)(out + base));
}

// fallback gather: uint2 adj (eid, other), sigmoid computed from ef on the fly
__global__ __launch_bounds__(256) void gather_ef(const float* __restrict__ x,
    const u16* __restrict__ h1, const u16* __restrict__ h2,
    const float* __restrict__ ef, const uint2* __restrict__ adj,
    const u32* __restrict__ rowstart, const float* __restrict__ g3,
    float* __restrict__ out, int N) {
  int row0 = (blockIdx.x * 256 + threadIdx.x) >> 6;
  if (row0 >= N) return;
  const int row = __builtin_amdgcn_readfirstlane(row0);
  const int lane = threadIdx.x & 63;
  const int d0 = lane * 2;
  const u32 beg = rowstart[row];
  const u32 end = rowstart[row + 1];
  float dx = 0.f, dy = 0.f, ax = 0.f, ay = 0.f;
  for (u32 j = beg; j < end; ++j) {
    uint2 en = adj[j];
    f32x2 e2 = *(const f32x2*)(ef + (size_t)en.x * DD + d0);
    u32 su = pack2(1.f / (1.f + __expf(-e2.x)), 1.f / (1.f + __expf(-e2.y)));
    u32 hu = *(const u32*)(h2 + (size_t)en.y * DD + d0);
    ACC2(su, hu)
  }
  const size_t base = (size_t)row * DD + d0;
  f32x2 xv = *(const f32x2*)(x + base);
  u32 h1u = *(const u32*)(h1 + base);
  f32x2 gv = *(const f32x2*)(g3 + d0);
  float i0 = bf2f((u16)(h1u & 0xffffu)) + ax / (dx + 1e-7f) + gv.x;
  float i1 = bf2f((u16)(h1u >> 16)) + ay / (dy + 1e-7f) + gv.y;
  float s = i0 + i1;
  float q = i0 * i0 + i1 * i1;
#pragma unroll
  for (int off = 32; off; off >>= 1) {
    s += __shfl_xor(s, off);
    q += __shfl_xor(q, off);
  }
  float mean = s * (1.f / 128.f);
  float var = q * (1.f / 128.f) - mean * mean;
  float rstd = rsqrtf(var + 1e-5f);
  float n0v = (i0 - mean) * rstd;
  float n1v = (i1 - mean) * rstd;
  f32x2 ov;
  ov.x = xv.x + (n0v > 0.f ? n0v : 0.f);
  ov.y = xv.y + (n1v > 0.f ? n1v : 0.f);
  *(f32x2*)(out + base) = ov;
}

extern "C" void kernel_launch(void* const* d_in, const int* in_sizes, int n_in,
                              void* d_out, int out_size, void* d_ws, size_t ws_size,
                              hipStream_t stream) {
  const float* x   = (const float*)d_in[0];
  const int*   eix = (const int*)d_in[1];
  const float* ef  = (const float*)d_in[2];
  const float* gf  = (const float*)d_in[3];
  const float* W1a = (const float*)d_in[4];
  const float* b1a = (const float*)d_in[5];
  const float* W1b = (const float*)d_in[6];
  const float* b1b = (const float*)d_in[7];
  const float* W2a = (const float*)d_in[8];
  const float* b2a = (const float*)d_in[9];
  const float* W2b = (const float*)d_in[10];
  const float* b2b = (const float*)d_in[11];
  const float* W3a = (const float*)d_in[12];
  const float* b3a = (const float*)d_in[13];
  const float* W3b = (const float*)d_in[14];
  const float* b3b = (const float*)d_in[15];

  const int N = in_sizes[0] / DD;
  const int E = in_sizes[2] / DD;

  char* p = (char*)d_ws;
  auto take = [&](size_t bytes) -> char* {
    char* r = p;
    p += (bytes + 255) & ~(size_t)255;
    return r;
  };
  u16* xb    = (u16*)take((size_t)N * DD * 2);
  u16* w1aT  = (u16*)take((size_t)DD * HH * 2);
  u16* w1bT  = (u16*)take((size_t)DD * HH * 2);
  u16* w2aT  = (u16*)take((size_t)DD * HH * 2);
  u16* w2bT  = (u16*)take((size_t)DD * HH * 2);
  u16* hidb  = (u16*)take((size_t)N * HH * 2);
  u16* h1b   = (u16*)take((size_t)N * DD * 2);
  u16* h2b   = (u16*)take((size_t)N * DD * 2);
  u32* deg   = (u32*)take((size_t)N * 4);
  u32* rowst = (u32*)take((size_t)(N + 1) * 4);
  u32* curs  = (u32*)take((size_t)N * 4);
  float* g3  = (float*)take((size_t)DD * 4);
  u32* adjO  = (u32*)take((size_t)2 * E * 4);
  uint2* prc = (uint2*)take((size_t)E * 8);
  size_t sBytes = (size_t)2 * E * DD * 2;   // sPerm: one 128-bf16 row per CSR slot
  bool useS = ((size_t)(p - (char*)d_ws) + sBytes) <= ws_size;
  u32* sPerm = useS ? (u32*)take(sBytes) : nullptr;
  // fallback layout overlaps adjO/prc space with a uint2 adj
  uint2* adjF = (uint2*)adjO;   // only used when !useS; needs 2E*8 — re-take
  if (!useS) { p = (char*)adjO; adjF = (uint2*)take((size_t)2 * E * 8); }

  hipMemsetAsync(deg, 0, (size_t)N * 4, stream);

  conv8_f32_bf16<<<2048, 256, 0, stream>>>(x, (uint4*)xb, N * DD / 8);
  transpose_all<<<512, 256, 0, stream>>>(W1a, W1b, W2a, W2b, w1aT, w1bT, w2aT, w2bT);
  g3_kernel<<<1, 256, 0, stream>>>(gf, W3a, b3a, W3b, b3b, g3);

  // CSR build
  count_kernel<<<2048, 256, 0, stream>>>(eix, deg, 2 * E);
  scan_kernel<<<1, 1024, 0, stream>>>(deg, rowst, curs, N);
  if (useS)
    scatter_kernel<<<2048, 256, 0, stream>>>(eix, curs, adjO, prc, E);
  else
    scatter_eid<<<2048, 256, 0, stream>>>(eix, curs, adjF, E);

  // FCNNs (B-frags register-resident across the M sweep)
  gemm_w64<128, HH, true ><<<1024, 256, 0, stream>>>(xb,   w1aT, b1a, hidb, N);
  gemm_w64<256, DD, false><<< 512, 256, 0, stream>>>(hidb, w1bT, b1b, h1b,  N);
  gemm_w64<128, HH, true ><<<1024, 256, 0, stream>>>(xb,   w2aT, b2a, hidb, N);
  gemm_w64<256, DD, false><<< 512, 256, 0, stream>>>(hidb, w2bT, b2b, h2b,  N);

  if (useS) {
    // permuted sigmoid right before gather so sPerm is L3-warm
    sigmoid_scatter<<<(E + 3) / 4, 256, 0, stream>>>(ef, prc, sPerm, E);
    gather_seq<<<(N + 3) / 4, 256, 0, stream>>>(x, h1b, h2b, sPerm, adjO, rowst, g3,
                                                (float*)d_out, N);
  } else {
    gather_ef<<<(N + 3) / 4, 256, 0, stream>>>(x, h1b, h2b, ef, adjF, rowst, g3,
                                               (float*)d_out, N);
  }
}

// Round 8
// 465.792 us; speedup vs baseline: 1.2768x; 1.0607x over previous
//
#include <hip/hip_runtime.h>
#include <math.h>

#define DD 128
#define HH 256

typedef __attribute__((ext_vector_type(8))) short bf16x8;
typedef __attribute__((ext_vector_type(4))) float f32x4;
typedef __attribute__((ext_vector_type(2))) float f32x2;
typedef unsigned short u16;
typedef unsigned int u32;

__device__ __forceinline__ float bf2f(u16 u) {
  union { u32 i; float f; } v; v.i = ((u32)u) << 16; return v.f;
}
__device__ __forceinline__ u16 f2bf(float f) {
  union { u32 i; float f; } v; v.f = f;
  u32 r = v.i + 0x7FFFu + ((v.i >> 16) & 1u);
  return (u16)(r >> 16);
}
__device__ __forceinline__ u32 pack2(float a, float b) {
  return (u32)f2bf(a) | ((u32)f2bf(b) << 16);
}

// vectorized sigmoid(f32) -> bf16; ef reads nontemporal (don't evict sbf from L3)
__global__ __launch_bounds__(256) void sigmoid8_f32_bf16(const float* __restrict__ in,
                                                         uint4* __restrict__ out, int n8) {
  int i = blockIdx.x * 256 + threadIdx.x;
  int stride = gridDim.x * 256;
  for (; i < n8; i += stride) {
    const f32x4 a = __builtin_nontemporal_load(((const f32x4*)in) + i * 2);
    const f32x4 b = __builtin_nontemporal_load(((const f32x4*)in) + i * 2 + 1);
    float s0 = 1.f / (1.f + __expf(-a.x));
    float s1 = 1.f / (1.f + __expf(-a.y));
    float s2 = 1.f / (1.f + __expf(-a.z));
    float s3 = 1.f / (1.f + __expf(-a.w));
    float s4 = 1.f / (1.f + __expf(-b.x));
    float s5 = 1.f / (1.f + __expf(-b.y));
    float s6 = 1.f / (1.f + __expf(-b.z));
    float s7 = 1.f / (1.f + __expf(-b.w));
    out[i] = make_uint4(pack2(s0, s1), pack2(s2, s3), pack2(s4, s5), pack2(s6, s7));
  }
}

// all 4 weight transposes in one launch: [K][N] f32 -> [N][K] bf16
__global__ __launch_bounds__(256) void transpose_all(
    const float* __restrict__ W1a, const float* __restrict__ W1b,
    const float* __restrict__ W2a, const float* __restrict__ W2b,
    u16* __restrict__ o1, u16* __restrict__ o2,
    u16* __restrict__ o3, u16* __restrict__ o4) {
  const int total = 4 * DD * HH;
  int idx = blockIdx.x * 256 + threadIdx.x;
  int stride = gridDim.x * 256;
  for (; idx < total; idx += stride) {
    int m = idx >> 15;          // DD*HH = 32768
    int r = idx & 32767;
    const float* in; u16* out; int K, Nc;
    if (m == 0)      { in = W1a; out = o1; K = DD; Nc = HH; }
    else if (m == 1) { in = W1b; out = o2; K = HH; Nc = DD; }
    else if (m == 2) { in = W2a; out = o3; K = DD; Nc = HH; }
    else             { in = W2b; out = o4; K = HH; Nc = DD; }
    int k = r / Nc, n = r % Nc;
    out[n * K + k] = f2bf(in[r]);
  }
}

// tiny FCNN on the global feature vector (fp32, one block)
__global__ __launch_bounds__(256) void g3_kernel(const float* __restrict__ g,
    const float* __restrict__ W3a, const float* __restrict__ b3a,
    const float* __restrict__ W3b, const float* __restrict__ b3b,
    float* __restrict__ g3out) {
  __shared__ float gs[DD];
  __shared__ float hs[HH];
  int t = threadIdx.x;
  if (t < DD) gs[t] = g[t];
  __syncthreads();
  float acc = b3a[t];
  for (int k = 0; k < DD; ++k) acc = fmaf(gs[k], W3a[k * HH + t], acc);
  hs[t] = acc > 0.f ? acc : 0.f;
  __syncthreads();
  if (t < DD) {
    float o = b3b[t];
    for (int j = 0; j < HH; ++j) o = fmaf(hs[j], W3b[j * DD + t], o);
    g3out[t] = o;
  }
}

// Layer 1 of BOTH FCNNs in one kernel. A = x (fp32, converted in-regs).
// hid layout [M][512]: cols 0..255 = relu(x@W1a+b1a), 256..511 = relu(x@W2a+b2a).
// One wave: 16 rows x 64 cols; B-frags register-resident across the M sweep.
__global__ __launch_bounds__(256) void gemm_l1(const float* __restrict__ x,
    const u16* __restrict__ w1aT, const float* __restrict__ b1a,
    const u16* __restrict__ w2aT, const float* __restrict__ b2a,
    u16* __restrict__ hid, int M) {
  const int wave = (blockIdx.x * 256 + threadIdx.x) >> 6;
  const int lane = threadIdx.x & 63;
  const int totalWaves = (gridDim.x * 256) >> 6;
  const int nc = wave & 7;           // 8 chunks of 64 cols
  const int mw = wave >> 3;
  const int mStride = totalWaves >> 3;
  const int which = nc >> 2;
  const int c0 = (nc & 3) * 64;
  const u16* wT = which ? w2aT : w1aT;
  const float* bs = which ? b2a : b1a;
  const int l15 = lane & 15, l4 = lane >> 4;

  bf16x8 bfrag[4][4];
  float bcol[4];
#pragma unroll
  for (int t = 0; t < 4; ++t) {
    const int col = c0 + t * 16 + l15;
    const u16* bb = wT + (size_t)col * DD + l4 * 8;
#pragma unroll
    for (int kb = 0; kb < 4; ++kb) bfrag[kb][t] = *(const bf16x8*)(bb + kb * 32);
    bcol[t] = bs[col];
  }

  const int mTiles = (M + 15) >> 4;
  for (int mt = mw; mt < mTiles; mt += mStride) {
    const int m0 = mt << 4;
    int rowA = m0 + l15; if (rowA >= M) rowA = M - 1;
    const float* xr = x + (size_t)rowA * DD + l4 * 8;
    bf16x8 ax[4];
#pragma unroll
    for (int kb = 0; kb < 4; ++kb) {
      f32x4 a = *(const f32x4*)(xr + kb * 32);
      f32x4 b = *(const f32x4*)(xr + kb * 32 + 4);
      bf16x8 v;
      v[0] = (short)f2bf(a.x); v[1] = (short)f2bf(a.y);
      v[2] = (short)f2bf(a.z); v[3] = (short)f2bf(a.w);
      v[4] = (short)f2bf(b.x); v[5] = (short)f2bf(b.y);
      v[6] = (short)f2bf(b.z); v[7] = (short)f2bf(b.w);
      ax[kb] = v;
    }
    f32x4 acc[4] = {{0,0,0,0},{0,0,0,0},{0,0,0,0},{0,0,0,0}};
#pragma unroll
    for (int kb = 0; kb < 4; ++kb)
#pragma unroll
      for (int t = 0; t < 4; ++t)
        acc[t] = __builtin_amdgcn_mfma_f32_16x16x32_bf16(ax[kb], bfrag[kb][t], acc[t], 0, 0, 0);
#pragma unroll
    for (int t = 0; t < 4; ++t)
#pragma unroll
      for (int r = 0; r < 4; ++r) {
        const int row = m0 + l4 * 4 + r;
        float v = acc[t][r] + bcol[t];
        v = v > 0.f ? v : 0.f;
        if (row < M) hid[(size_t)row * 512 + which * 256 + c0 + t * 16 + l15] = f2bf(v);
      }
  }
}

// Layer 2 of BOTH FCNNs: h1 = hid[:, :256]@W1b + b1b ; h2 = hid[:, 256:]@W2b + b2b.
__global__ __launch_bounds__(256) void gemm_l2(const u16* __restrict__ hid,
    const u16* __restrict__ w1bT, const float* __restrict__ b1b,
    const u16* __restrict__ w2bT, const float* __restrict__ b2b,
    u16* __restrict__ h1, u16* __restrict__ h2, int M) {
  const int wave = (blockIdx.x * 256 + threadIdx.x) >> 6;
  const int lane = threadIdx.x & 63;
  const int totalWaves = (gridDim.x * 256) >> 6;
  const int nc = wave & 3;           // 4 chunks of 64 cols (h1:0,1  h2:2,3)
  const int mw = wave >> 2;
  const int mStride = totalWaves >> 2;
  const int which = nc >> 1;
  const int c0 = (nc & 1) * 64;
  const u16* wT = which ? w2bT : w1bT;
  const float* bs = which ? b2b : b1b;
  u16* Dst = which ? h2 : h1;
  const int l15 = lane & 15, l4 = lane >> 4;

  bf16x8 bfrag[8][4];
  float bcol[4];
#pragma unroll
  for (int t = 0; t < 4; ++t) {
    const int col = c0 + t * 16 + l15;
    const u16* bb = wT + (size_t)col * HH + l4 * 8;
#pragma unroll
    for (int kb = 0; kb < 8; ++kb) bfrag[kb][t] = *(const bf16x8*)(bb + kb * 32);
    bcol[t] = bs[col];
  }

  const int mTiles = (M + 15) >> 4;
  for (int mt = mw; mt < mTiles; mt += mStride) {
    const int m0 = mt << 4;
    int rowA = m0 + l15; if (rowA >= M) rowA = M - 1;
    const u16* arow = hid + (size_t)rowA * 512 + which * 256 + l4 * 8;
    f32x4 acc[4] = {{0,0,0,0},{0,0,0,0},{0,0,0,0},{0,0,0,0}};
#pragma unroll
    for (int kb = 0; kb < 8; ++kb) {
      bf16x8 afrag = *(const bf16x8*)(arow + kb * 32);
#pragma unroll
      for (int t = 0; t < 4; ++t)
        acc[t] = __builtin_amdgcn_mfma_f32_16x16x32_bf16(afrag, bfrag[kb][t], acc[t], 0, 0, 0);
    }
#pragma unroll
    for (int t = 0; t < 4; ++t)
#pragma unroll
      for (int r = 0; r < 4; ++r) {
        const int row = m0 + l4 * 4 + r;
        if (row < M) Dst[(size_t)row * DD + c0 + t * 16 + l15] = f2bf(acc[t][r] + bcol[t]);
      }
  }
}

// ---- CSR build ----
__global__ __launch_bounds__(256) void count_kernel(const int* __restrict__ eix,
                                                    u32* __restrict__ deg, int twoE) {
  int t = blockIdx.x * 256 + threadIdx.x;
  int stride = gridDim.x * 256;
  for (; t < twoE; t += stride) atomicAdd(&deg[eix[t]], 1u);
}

// 16-wave coalesced two-pass scan (single block)
__global__ __launch_bounds__(1024) void scan_kernel(const u32* __restrict__ deg,
    u32* __restrict__ rowstart, u32* __restrict__ cursor, int N) {
  __shared__ u32 wsum[16];
  const int t = threadIdx.x;
  const int w = t >> 6, lane = t & 63;
  const int span = ((N + 1023) & ~1023) >> 4;   // multiple of 64
  const int b = w * span;
  const int e = min(b + span, N);

  u32 s = 0;
  for (int i = b + lane; i < e; i += 64) s += deg[i];
#pragma unroll
  for (int off = 32; off; off >>= 1) s += __shfl_xor(s, off);
  if (lane == 0) wsum[w] = s;
  __syncthreads();

  u32 carry = 0;
  for (int i = 0; i < w; ++i) carry += wsum[i];

  for (int i0 = b; i0 < e; i0 += 64) {
    int i = i0 + lane;
    u32 v = (i < e) ? deg[i] : 0u;
    u32 inc = v;
#pragma unroll
    for (int off = 1; off < 64; off <<= 1) {
      u32 u2 = __shfl_up(inc, off);
      if (lane >= off) inc += u2;
    }
    u32 excl = carry + inc - v;
    if (i < e) { rowstart[i] = excl; cursor[i] = excl; }
    carry += __shfl(inc, 63);
  }
  if (w == 15 && lane == 63) rowstart[N] = carry;
}

__global__ __launch_bounds__(256) void scatter_kernel(const int* __restrict__ eix,
    u32* __restrict__ cursor, uint2* __restrict__ adj, int E) {
  int t = blockIdx.x * 256 + threadIdx.x;
  int stride = gridDim.x * 256;
  int twoE = 2 * E;
  for (; t < twoE; t += stride) {
    int node, eid, other;
    if (t < E) { node = eix[t]; eid = t;     other = eix[t + E]; }
    else       { node = eix[t]; eid = t - E; other = eix[t - E]; }
    u32 pos = atomicAdd(&cursor[node], 1u);
    adj[pos] = make_uint2((u32)eid, (u32)other);
  }
}

// ---- gather: one BLOCK (4 waves) per node row ----
#define ACC2(su, hu)                                        \
  {                                                         \
    float sx_ = bf2f((u16)((su) & 0xffffu));                \
    float sy_ = bf2f((u16)((su) >> 16));                    \
    dx += sx_; dy += sy_;                                   \
    ax = fmaf(sx_, bf2f((u16)((hu) & 0xffffu)), ax);        \
    ay = fmaf(sy_, bf2f((u16)((hu) >> 16)), ay);            \
  }

template<bool SB>
__global__ __launch_bounds__(256) void gather_block(const float* __restrict__ x,
    const u16* __restrict__ h1, const u16* __restrict__ h2,
    const float* __restrict__ ef, const u16* __restrict__ sbf,
    const uint2* __restrict__ adj, const u32* __restrict__ rowstart,
    const float* __restrict__ g3, float* __restrict__ out, int N) {
  const int row = blockIdx.x;
  const int w = threadIdx.x >> 6;
  const int lane = threadIdx.x & 63;
  const int d0 = lane * 2;
  __shared__ f32x4 part[4][64];

  const u32 beg = rowstart[row];
  const u32 end = rowstart[row + 1];

  float dx = 0.f, dy = 0.f, ax = 0.f, ay = 0.f;
  u32 j = beg + w;
  // two visits per iteration (j, j+4), 4 waves stride the edge list
  for (; j + 4 < end; j += 8) {
    const uint2 e0 = adj[j];
    const uint2 e1 = adj[j + 4];
    u32 s0, s1;
    if (SB) {
      s0 = *(const u32*)(sbf + (size_t)e0.x * DD + d0);
      s1 = *(const u32*)(sbf + (size_t)e1.x * DD + d0);
    } else {
      f32x2 v0 = *(const f32x2*)(ef + (size_t)e0.x * DD + d0);
      f32x2 v1 = *(const f32x2*)(ef + (size_t)e1.x * DD + d0);
      s0 = pack2(1.f / (1.f + __expf(-v0.x)), 1.f / (1.f + __expf(-v0.y)));
      s1 = pack2(1.f / (1.f + __expf(-v1.x)), 1.f / (1.f + __expf(-v1.y)));
    }
    const u32 hv0 = *(const u32*)(h2 + (size_t)e0.y * DD + d0);
    const u32 hv1 = *(const u32*)(h2 + (size_t)e1.y * DD + d0);
    ACC2(s0, hv0) ACC2(s1, hv1)
  }
  if (j < end) {
    const uint2 e0 = adj[j];
    u32 s0;
    if (SB) {
      s0 = *(const u32*)(sbf + (size_t)e0.x * DD + d0);
    } else {
      f32x2 v0 = *(const f32x2*)(ef + (size_t)e0.x * DD + d0);
      s0 = pack2(1.f / (1.f + __expf(-v0.x)), 1.f / (1.f + __expf(-v0.y)));
    }
    const u32 hv0 = *(const u32*)(h2 + (size_t)e0.y * DD + d0);
    ACC2(s0, hv0)
  }

  f32x4 mine; mine.x = dx; mine.y = dy; mine.z = ax; mine.w = ay;
  part[w][lane] = mine;
  __syncthreads();
  if (w != 0) return;

  f32x4 p = part[0][lane];
  p += part[1][lane];
  p += part[2][lane];
  p += part[3][lane];

  const size_t base = (size_t)row * DD + d0;
  f32x2 xv = __builtin_nontemporal_load((const f32x2*)(x + base));
  u32 h1u = __builtin_nontemporal_load((const u32*)(h1 + base));
  f32x2 gv = *(const f32x2*)(g3 + d0);

  float i0 = bf2f((u16)(h1u & 0xffffu)) + p.z / (p.x + 1e-7f) + gv.x;
  float i1 = bf2f((u16)(h1u >> 16)) + p.w / (p.y + 1e-7f) + gv.y;

  float s = i0 + i1;
  float q = i0 * i0 + i1 * i1;
#pragma unroll
  for (int off = 32; off; off >>= 1) {
    s += __shfl_xor(s, off);
    q += __shfl_xor(q, off);
  }
  float mean = s * (1.f / 128.f);
  float var = q * (1.f / 128.f) - mean * mean;
  float rstd = rsqrtf(var + 1e-5f);
  float n0v = (i0 - mean) * rstd;
  float n1v = (i1 - mean) * rstd;
  f32x2 ov;
  ov.x = xv.x + (n0v > 0.f ? n0v : 0.f);
  ov.y = xv.y + (n1v > 0.f ? n1v : 0.f);
  __builtin_nontemporal_store(ov, (f32x2*)(out + base));
}

extern "C" void kernel_launch(void* const* d_in, const int* in_sizes, int n_in,
                              void* d_out, int out_size, void* d_ws, size_t ws_size,
                              hipStream_t stream) {
  const float* x   = (const float*)d_in[0];
  const int*   eix = (const int*)d_in[1];
  const float* ef  = (const float*)d_in[2];
  const float* gf  = (const float*)d_in[3];
  const float* W1a = (const float*)d_in[4];
  const float* b1a = (const float*)d_in[5];
  const float* W1b = (const float*)d_in[6];
  const float* b1b = (const float*)d_in[7];
  const float* W2a = (const float*)d_in[8];
  const float* b2a = (const float*)d_in[9];
  const float* W2b = (const float*)d_in[10];
  const float* b2b = (const float*)d_in[11];
  const float* W3a = (const float*)d_in[12];
  const float* b3a = (const float*)d_in[13];
  const float* W3b = (const float*)d_in[14];
  const float* b3b = (const float*)d_in[15];

  const int N = in_sizes[0] / DD;
  const int E = in_sizes[2] / DD;

  char* p = (char*)d_ws;
  auto take = [&](size_t bytes) -> char* {
    char* r = p;
    p += (bytes + 255) & ~(size_t)255;
    return r;
  };
  u16* w1aT  = (u16*)take((size_t)DD * HH * 2);
  u16* w1bT  = (u16*)take((size_t)DD * HH * 2);
  u16* w2aT  = (u16*)take((size_t)DD * HH * 2);
  u16* w2bT  = (u16*)take((size_t)DD * HH * 2);
  u16* hidb  = (u16*)take((size_t)N * 512 * 2);
  u16* h1b   = (u16*)take((size_t)N * DD * 2);
  u16* h2b   = (u16*)take((size_t)N * DD * 2);
  u32* deg   = (u32*)take((size_t)N * 4);
  u32* rowst = (u32*)take((size_t)(N + 1) * 4);
  u32* curs  = (u32*)take((size_t)N * 4);
  float* g3  = (float*)take((size_t)DD * 4);
  uint2* adj = (uint2*)take((size_t)2 * E * 8);
  size_t sBytes = (size_t)E * DD * 2;
  bool useS = ((size_t)(p - (char*)d_ws) + sBytes) <= ws_size;
  u16* sbf = useS ? (u16*)take(sBytes) : nullptr;

  hipMemsetAsync(deg, 0, (size_t)N * 4, stream);

  transpose_all<<<512, 256, 0, stream>>>(W1a, W1b, W2a, W2b, w1aT, w1bT, w2aT, w2bT);
  g3_kernel<<<1, 256, 0, stream>>>(gf, W3a, b3a, W3b, b3b, g3);

  // CSR build
  count_kernel<<<2048, 256, 0, stream>>>(eix, deg, 2 * E);
  scan_kernel<<<1, 1024, 0, stream>>>(deg, rowst, curs, N);
  scatter_kernel<<<2048, 256, 0, stream>>>(eix, curs, adj, E);

  // FCNNs: 2 fused launches (x read fp32 in gemm_l1; both hidden layers in hidb)
  gemm_l1<<<1024, 256, 0, stream>>>(x, w1aT, b1a, w2aT, b2a, hidb, N);
  gemm_l2<<<1024, 256, 0, stream>>>(hidb, w1bT, b1b, w2bT, b2b, h1b, h2b, N);

  // sigmoid last so sbf is L3-resident for gather
  if (useS) sigmoid8_f32_bf16<<<4096, 256, 0, stream>>>(ef, (uint4*)sbf, E * DD / 8);

  if (useS)
    gather_block<true ><<<N, 256, 0, stream>>>(x, h1b, h2b, ef, sbf, adj, rowst, g3,
                                               (float*)d_out, N);
  else
    gather_block<false><<<N, 256, 0, stream>>>(x, h1b, h2b, ef, nullptr, adj, rowst, g3,
                                               (float*)d_out, N);
}